// Round 2
// baseline (410.021 us; speedup 1.0000x reference)
//
#include <hip/hip_runtime.h>
#include <hip/hip_bf16.h>

typedef unsigned short u16;
typedef __attribute__((ext_vector_type(8))) short short8;
typedef __attribute__((ext_vector_type(4))) short s4;
typedef __attribute__((ext_vector_type(4))) float floatx4;

__device__ __forceinline__ float lrelu(float x) { return x > 0.f ? x : 0.01f * x; }

__device__ __forceinline__ short bf16bits(float v) {
  __hip_bfloat16 t = __float2bfloat16(v);
  return *reinterpret_cast<short*>(&t);
}
__device__ __forceinline__ float bits2f(u16 b) {
  __hip_bfloat16 t = *reinterpret_cast<__hip_bfloat16*>(&b);
  return __bfloat162float(t);
}
__device__ __forceinline__ short8 pack8(floatx4 x0, floatx4 x1) {
  short8 b;
#pragma unroll
  for (int r = 0; r < 4; ++r) { b[r] = bf16bits(x0[r]); b[4 + r] = bf16bits(x1[r]); }
  return b;
}

__device__ __forceinline__ void gload_lds16(const void* g, void* lds) {
  __builtin_amdgcn_global_load_lds(
      (const __attribute__((address_space(1))) unsigned int*)g,
      (__attribute__((address_space(3))) unsigned int*)lds, 16, 0, 0);
}

// ---------------------------------------------------------------------------
// Batched transpose+convert: 6 weights W[K][N] f32 -> Wt[N][K] bf16, 1 launch.
// ---------------------------------------------------------------------------
__global__ __launch_bounds__(256) void transpose_all(
    const float* __restrict__ W1, const float* __restrict__ W2,
    const float* __restrict__ W3, const float* __restrict__ W4,
    const float* __restrict__ W5, const float* __restrict__ W6,
    u16* __restrict__ T1, u16* __restrict__ T2, u16* __restrict__ T3,
    u16* __restrict__ T4, u16* __restrict__ T5, u16* __restrict__ T6) {
  const float* W; u16* T; int K, N;
  switch (blockIdx.z) {
    case 0: W = W1; T = T1; K = 128; N = 512; break;
    case 1: W = W2; T = T2; K = 512; N = 512; break;
    case 2: W = W3; T = T3; K = 512; N = 256; break;
    case 3: W = W4; T = T4; K = 256; N = 512; break;
    case 4: W = W5; T = T5; K = 512; N = 512; break;
    default: W = W6; T = T6; K = 512; N = 256; break;
  }
  if ((int)blockIdx.x >= N / 32 || (int)blockIdx.y >= K / 32) return;
  __shared__ u16 tile[32][33];
  const int tx = threadIdx.x & 31;
  const int ty = threadIdx.x >> 5;
  const int n0 = blockIdx.x * 32;
  const int k0 = blockIdx.y * 32;
  for (int i = ty; i < 32; i += 8)
    tile[i][tx] = (u16)bf16bits(W[(size_t)(k0 + i) * N + n0 + tx]);
  __syncthreads();
  for (int i = ty; i < 32; i += 8)
    T[(size_t)(n0 + i) * K + k0 + tx] = tile[tx][i];
}

// ---------------------------------------------------------------------------
// Counting sort of node ids by dag id (2000 bins).
// ---------------------------------------------------------------------------
__global__ __launch_bounds__(256) void hist_kernel(const int* __restrict__ dag,
                                                   int* __restrict__ hist, int n) {
  int i = blockIdx.x * blockDim.x + threadIdx.x;
  if (i < n) atomicAdd(&hist[dag[i]], 1);
}

__global__ __launch_bounds__(256) void scan_offsets(const int* __restrict__ hist,
                                                    int* __restrict__ cursor) {
  __shared__ int part[256];
  const int t = threadIdx.x;
  const int base = t * 8;
  int loc[8];
  int s = 0;
#pragma unroll
  for (int j = 0; j < 8; ++j) {
    int v = (base + j < 2000) ? hist[base + j] : 0;
    loc[j] = s;
    s += v;
  }
  part[t] = s;
  __syncthreads();
  int val = s;
  for (int off = 1; off < 256; off <<= 1) {
    int tmp = (t >= off) ? part[t - off] : 0;
    __syncthreads();
    val += tmp;
    part[t] = val;
    __syncthreads();
  }
  const int chunkBase = (t == 0) ? 0 : part[t - 1];
#pragma unroll
  for (int j = 0; j < 8; ++j)
    if (base + j < 2000) cursor[base + j] = chunkBase + loc[j];
}

__global__ __launch_bounds__(256) void scatter_kernel(const int* __restrict__ dag,
                                                      int* __restrict__ cursor,
                                                      int* __restrict__ perm,
                                                      int* __restrict__ dsort, int n) {
  int i = blockIdx.x * blockDim.x + threadIdx.x;
  if (i < n) {
    int d = dag[i];
    int p = atomicAdd(&cursor[d], 1);
    perm[p] = i;
    dsort[p] = d;
  }
}

// ---------------------------------------------------------------------------
// Xb[i][k] = bf16(X[perm[i]][k]) — gather X into sorted order, f32 -> bf16.
// ---------------------------------------------------------------------------
__global__ __launch_bounds__(256) void xb_conv(const float* __restrict__ X,
                                               const int* __restrict__ perm,
                                               u16* __restrict__ Xb, int n) {
  int t = blockIdx.x * 256 + threadIdx.x;
  if (t < n * 32) {
    int row = t >> 5, kk = (t & 31) * 4;
    int src = perm[row];
    floatx4 x = *(const floatx4*)(X + (size_t)src * 128 + kk);
    s4 h;
#pragma unroll
    for (int r = 0; r < 4; ++r) h[r] = bf16bits(x[r]);
    *(s4*)(Xb + (size_t)row * 128 + kk) = h;
  }
}

// ---------------------------------------------------------------------------
// Fully fused node stack, occupancy-tuned: 64 rows/block, 512 thr (8 waves),
// LDS 66.5 KB -> 2 blocks/CU -> 16 waves/CU (4/SIMD) for latency hiding.
//   L1: H1 = lrelu(Xb@W1+b1)   K=128  (Xb + W1 straight from global/L2)
//   L2: H2 = lrelu(H1@W2+b2)   K=512  (acts from LDS, W2 from L2, no staging)
//   L3: G  = lrelu(H2@W3+b3)   K=512  -> LDS, segmented dag-sum -> atomics s1
// No af prefetch: acc[4][4]=64 VGPR + af/bx keeps us in the 128-reg/16-wave
// tier (__launch_bounds__(512,4)); 4 waves/SIMD hide LDS+L2 latency (TLP).
// H pitch 520 u16: row stride/4 = 260 == 4 (mod 32) -> 2-way max on b128 = free.
// Seg-walk batches 8 LDS reads per unrolled group (1 LDS latency per 8 rows).
// Operand convention (harness-verified): mfma(af, bx, acc) -> out row =
// bx-row (mi*16+m16), out col = af-row (ni*16+quad*4+r).
// ---------------------------------------------------------------------------
#define NODE_NP 520
#define NODE_P3 264
#define NODE_ROWS 64
#define NODE_LDS (NODE_ROWS * NODE_NP * 2)   // 66560 B -> 2 blocks/CU

__global__ __launch_bounds__(512, 4) void node_fused(
    const u16* __restrict__ Xb, const u16* __restrict__ W1t,
    const u16* __restrict__ W2t, const u16* __restrict__ W3t,
    const float* __restrict__ b1, const float* __restrict__ b2,
    const float* __restrict__ b3, float* __restrict__ s1,
    const int* __restrict__ dsort) {
  extern __shared__ __align__(16) char lds[];
  u16* H = (u16*)lds;   // [64][NODE_NP] for H1/H2, reused as [64][NODE_P3] for L3

  const int tid  = threadIdx.x;
  const int wv   = tid >> 6;
  const int lane = tid & 63;
  const int m16  = lane & 15;
  const int quad = lane >> 4;
  const int row0 = blockIdx.x * NODE_ROWS;

  // ---- layer 1: K=128, N=512; wave cols [wv*64, wv*64+64), rows 0..63
  {
    const u16* ap = Xb + (size_t)(row0 + m16) * 128 + quad * 8;
    const u16* wp = W1t + (size_t)(wv * 64 + m16) * 128 + quad * 8;
    floatx4 acc[4][4];
#pragma unroll
    for (int i = 0; i < 4; ++i)
#pragma unroll
      for (int j = 0; j < 4; ++j) { floatx4 z = {0.f, 0.f, 0.f, 0.f}; acc[i][j] = z; }
#pragma unroll
    for (int s = 0; s < 4; ++s) {
      short8 af[4], bx[4];
#pragma unroll
      for (int ni = 0; ni < 4; ++ni) af[ni] = *(const short8*)(wp + ni * 2048 + s * 32);
#pragma unroll
      for (int mi = 0; mi < 4; ++mi) bx[mi] = *(const short8*)(ap + mi * 2048 + s * 32);
#pragma unroll
      for (int ni = 0; ni < 4; ++ni)
#pragma unroll
        for (int mi = 0; mi < 4; ++mi)
          acc[ni][mi] = __builtin_amdgcn_mfma_f32_16x16x32_bf16(af[ni], bx[mi], acc[ni][mi], 0, 0, 0);
    }
    const int n0 = wv * 64;
#pragma unroll
    for (int ni = 0; ni < 4; ++ni) {
      const int nb = n0 + ni * 16 + quad * 4;
      floatx4 bb = *(const floatx4*)&b1[nb];
#pragma unroll
      for (int mi = 0; mi < 4; ++mi) {
        s4 h;
#pragma unroll
        for (int r = 0; r < 4; ++r) h[r] = bf16bits(lrelu(acc[ni][mi][r] + bb[r]));
        *(s4*)&H[(size_t)(mi * 16 + m16) * NODE_NP + nb] = h;
      }
    }
  }
  __syncthreads();

  // ---- layer 2: K=512, N=512; acts from LDS, weights from L2
  {
    const u16* wp = W2t + (size_t)(wv * 64 + m16) * 512 + quad * 8;
    const u16* hp = H + (size_t)m16 * NODE_NP + quad * 8;
    floatx4 acc[4][4];
#pragma unroll
    for (int i = 0; i < 4; ++i)
#pragma unroll
      for (int j = 0; j < 4; ++j) { floatx4 z = {0.f, 0.f, 0.f, 0.f}; acc[i][j] = z; }
#pragma unroll 2
    for (int s = 0; s < 16; ++s) {
      short8 af[4], bx[4];
#pragma unroll
      for (int ni = 0; ni < 4; ++ni) af[ni] = *(const short8*)(wp + ni * 8192 + s * 32);
#pragma unroll
      for (int mi = 0; mi < 4; ++mi)
        bx[mi] = *(const short8*)(hp + mi * (16 * NODE_NP) + s * 32);
#pragma unroll
      for (int ni = 0; ni < 4; ++ni)
#pragma unroll
        for (int mi = 0; mi < 4; ++mi)
          acc[ni][mi] = __builtin_amdgcn_mfma_f32_16x16x32_bf16(af[ni], bx[mi], acc[ni][mi], 0, 0, 0);
    }
    __syncthreads();   // all waves done READING H1 before overwriting with H2
    const int n0 = wv * 64;
#pragma unroll
    for (int ni = 0; ni < 4; ++ni) {
      const int nb = n0 + ni * 16 + quad * 4;
      floatx4 bb = *(const floatx4*)&b2[nb];
#pragma unroll
      for (int mi = 0; mi < 4; ++mi) {
        s4 h;
#pragma unroll
        for (int r = 0; r < 4; ++r) h[r] = bf16bits(lrelu(acc[ni][mi][r] + bb[r]));
        *(s4*)&H[(size_t)(mi * 16 + m16) * NODE_NP + nb] = h;
      }
    }
  }
  __syncthreads();

  // ---- layer 3: K=512, N=256; wave cols [wv*32, wv*32+32)
  {
    const u16* wp = W3t + (size_t)(wv * 32 + m16) * 512 + quad * 8;
    const u16* hp = H + (size_t)m16 * NODE_NP + quad * 8;
    floatx4 acc[2][4];
#pragma unroll
    for (int i = 0; i < 2; ++i)
#pragma unroll
      for (int j = 0; j < 4; ++j) { floatx4 z = {0.f, 0.f, 0.f, 0.f}; acc[i][j] = z; }
#pragma unroll 2
    for (int s = 0; s < 16; ++s) {
      short8 af[2], bx[4];
#pragma unroll
      for (int ni = 0; ni < 2; ++ni) af[ni] = *(const short8*)(wp + ni * 8192 + s * 32);
#pragma unroll
      for (int mi = 0; mi < 4; ++mi)
        bx[mi] = *(const short8*)(hp + mi * (16 * NODE_NP) + s * 32);
#pragma unroll
      for (int ni = 0; ni < 2; ++ni)
#pragma unroll
        for (int mi = 0; mi < 4; ++mi)
          acc[ni][mi] = __builtin_amdgcn_mfma_f32_16x16x32_bf16(af[ni], bx[mi], acc[ni][mi], 0, 0, 0);
    }
    __syncthreads();   // all waves done reading H2
    const int n0 = wv * 32;
#pragma unroll
    for (int ni = 0; ni < 2; ++ni) {
      const int nb = n0 + ni * 16 + quad * 4;
      floatx4 bb = *(const floatx4*)&b3[nb];
#pragma unroll
      for (int mi = 0; mi < 4; ++mi) {
        s4 h;
#pragma unroll
        for (int r = 0; r < 4; ++r) h[r] = bf16bits(lrelu(acc[ni][mi][r] + bb[r]));
        *(s4*)&H[(size_t)(mi * 16 + m16) * NODE_P3 + nb] = h;
      }
    }
  }
  __syncthreads();

  // ---- segmented dag walk: wave wv owns rows [(wv>>2)*32, +32), cols
  // [(wv&3)*64, +64), lane = local col. 8-row batched LDS loads to pipeline.
  {
    const int rh = (wv >> 2) * 32;
    const int c0 = (wv & 3) * 64;
    const int myDag = dsort[row0 + rh + (lane & 31)];
    float* so = s1 + c0 + lane;
    float run = 0.f;
    int cur = __shfl(myDag, 0);
#pragma unroll
    for (int rb = 0; rb < 32; rb += 8) {
      float v[8];
#pragma unroll
      for (int j = 0; j < 8; ++j)
        v[j] = bits2f(H[(size_t)(rh + rb + j) * NODE_P3 + c0 + lane]);
#pragma unroll
      for (int j = 0; j < 8; ++j) {
        int d = __shfl(myDag, rb + j);              // wave-uniform
        if (d != cur) {
          if (cur >= 0) atomicAdd(so + (size_t)cur * 256, run);
          run = 0.f; cur = d;
        }
        run += v[j];
      }
    }
    if (cur >= 0) atomicAdd(so + (size_t)cur * 256, run);
  }
}

// ---------------------------------------------------------------------------
// Fused 3-layer global stack (2000 rows) + fused s2 = mask @ g3 reduction.
// g3 never materialized: each block reduces mask-weighted layer-3 outputs
// over its 32 rows (shfl_xor across the 16 row-lanes) -> 1 atomic per col.
// ---------------------------------------------------------------------------
#define ROWS 32
#define H_PITCH 520
#define HBYTES (ROWS * H_PITCH * 2)
#define WL_OFF (2 * HBYTES)
#define WL_HALF 16384
#define FUSED_LDS (WL_OFF + 65536 + 128)

template <int K1>
__global__ __launch_bounds__(512, 2) void fused3(
    const float* __restrict__ A0, const u16* __restrict__ W1t,
    const u16* __restrict__ W2t, const u16* __restrict__ W3t,
    const float* __restrict__ b1, const float* __restrict__ b2,
    const float* __restrict__ b3, const float* __restrict__ mask,
    float* __restrict__ out, int s2Off, int M) {
  extern __shared__ __align__(16) char ldsbuf[];
  u16* H1 = (u16*)ldsbuf;
  u16* H2 = (u16*)(ldsbuf + HBYTES);
  u16* Wl = (u16*)(ldsbuf + WL_OFF);

  const int tid  = threadIdx.x;
  const int wv   = tid >> 6;
  const int lane = tid & 63;
  const int m16  = lane & 15;
  const int quad = lane >> 4;
  const int row0 = blockIdx.x * ROWS;

  const int sr  = lane >> 2;
  const int skq = ((lane & 3) - (sr >> 1)) & 3;
  const int sw8 = (m16 * 4 + ((quad + (m16 >> 1)) & 3)) * 8;

  auto stage512 = [&](const u16* Wt, int K, int k0, int sel) {
    u16* base = Wl + sel * WL_HALF;
#pragma unroll
    for (int c = 0; c < 4; ++c) {
      int chunk = wv * 4 + c;
      gload_lds16(Wt + (size_t)(chunk * 16 + sr) * K + k0 + skq * 8,
                  base + chunk * 512);
    }
  };
  auto stage256 = [&](const u16* Wt, int K, int k0, int sel) {
    u16* base = Wl + sel * 8192;
#pragma unroll
    for (int c = 0; c < 2; ++c) {
      int chunk = wv * 2 + c;
      gload_lds16(Wt + (size_t)(chunk * 16 + sr) * K + k0 + skq * 8,
                  base + chunk * 512);
    }
  };

  int grow[2];
#pragma unroll
  for (int mi = 0; mi < 2; ++mi) {
    int r = row0 + mi * 16 + m16;
    grow[mi] = r < M ? r : (M - 1);
  }
  const float* ap[2];
#pragma unroll
  for (int mi = 0; mi < 2; ++mi) ap[mi] = A0 + (size_t)grow[mi] * K1 + quad * 8;

  {  // layer 1
    constexpr int NS1 = K1 / 32;
    stage512(W1t, K1, 0, 0);
    floatx4 acc[4][2];
#pragma unroll
    for (int i = 0; i < 4; i++)
#pragma unroll
      for (int j = 0; j < 2; j++) { floatx4 z = {0.f,0.f,0.f,0.f}; acc[i][j] = z; }
#pragma unroll
    for (int s = 0; s < NS1; ++s) {
      __syncthreads();
      if (s + 1 < NS1) stage512(W1t, K1, (s + 1) * 32, (s + 1) & 1);
      const u16* wb = Wl + (s & 1) * WL_HALF;
      short8 af[4], bx[2];
#pragma unroll
      for (int ni = 0; ni < 4; ++ni)
        af[ni] = *(const short8*)(wb + (wv * 4 + ni) * 512 + sw8);
#pragma unroll
      for (int mi = 0; mi < 2; ++mi)
        bx[mi] = pack8(*(const floatx4*)(ap[mi] + s * 32),
                       *(const floatx4*)(ap[mi] + s * 32 + 4));
#pragma unroll
      for (int ni = 0; ni < 4; ++ni)
#pragma unroll
        for (int mi = 0; mi < 2; ++mi)
          acc[ni][mi] = __builtin_amdgcn_mfma_f32_16x16x32_bf16(af[ni], bx[mi], acc[ni][mi], 0, 0, 0);
    }
    const int n0 = wv * 64;
#pragma unroll
    for (int ni = 0; ni < 4; ++ni) {
      const int nb = n0 + ni * 16 + quad * 4;
      floatx4 bb = *(const floatx4*)&b1[nb];
#pragma unroll
      for (int mi = 0; mi < 2; ++mi) {
        s4 h;
#pragma unroll
        for (int r = 0; r < 4; ++r) h[r] = bf16bits(lrelu(acc[ni][mi][r] + bb[r]));
        *(s4*)&H1[(mi * 16 + m16) * H_PITCH + nb] = h;
      }
    }
  }

  {  // layer 2
    stage512(W2t, 512, 0, 0);
    const u16* hp[2];
#pragma unroll
    for (int mi = 0; mi < 2; ++mi)
      hp[mi] = H1 + (mi * 16 + m16) * H_PITCH + quad * 8;
    floatx4 acc[4][2];
#pragma unroll
    for (int i = 0; i < 4; i++)
#pragma unroll
      for (int j = 0; j < 2; j++) { floatx4 z = {0.f,0.f,0.f,0.f}; acc[i][j] = z; }
    for (int s = 0; s < 16; ++s) {
      __syncthreads();
      if (s < 15) stage512(W2t, 512, (s + 1) * 32, (s + 1) & 1);
      const u16* wb = Wl + (s & 1) * WL_HALF;
      short8 af[4], bx[2];
#pragma unroll
      for (int ni = 0; ni < 4; ++ni)
        af[ni] = *(const short8*)(wb + (wv * 4 + ni) * 512 + sw8);
#pragma unroll
      for (int mi = 0; mi < 2; ++mi) bx[mi] = *(const short8*)(hp[mi] + s * 32);
#pragma unroll
      for (int ni = 0; ni < 4; ++ni)
#pragma unroll
        for (int mi = 0; mi < 2; ++mi)
          acc[ni][mi] = __builtin_amdgcn_mfma_f32_16x16x32_bf16(af[ni], bx[mi], acc[ni][mi], 0, 0, 0);
    }
    const int n0 = wv * 64;
#pragma unroll
    for (int ni = 0; ni < 4; ++ni) {
      const int nb = n0 + ni * 16 + quad * 4;
      floatx4 bb = *(const floatx4*)&b2[nb];
#pragma unroll
      for (int mi = 0; mi < 2; ++mi) {
        s4 h;
#pragma unroll
        for (int r = 0; r < 4; ++r) h[r] = bf16bits(lrelu(acc[ni][mi][r] + bb[r]));
        *(s4*)&H2[(mi * 16 + m16) * H_PITCH + nb] = h;
      }
    }
  }

  {  // layer 3 + fused s2 contribution
    stage256(W3t, 512, 0, 0);
    const u16* hp[2];
#pragma unroll
    for (int mi = 0; mi < 2; ++mi)
      hp[mi] = H2 + (mi * 16 + m16) * H_PITCH + quad * 8;
    floatx4 acc[2][2];
#pragma unroll
    for (int i = 0; i < 2; i++)
#pragma unroll
      for (int j = 0; j < 2; j++) { floatx4 z = {0.f,0.f,0.f,0.f}; acc[i][j] = z; }
    for (int s = 0; s < 16; ++s) {
      __syncthreads();
      if (s < 15) stage256(W3t, 512, (s + 1) * 32, (s + 1) & 1);
      const u16* wb = Wl + (s & 1) * 8192;
      short8 af[2], bx[2];
#pragma unroll
      for (int ni = 0; ni < 2; ++ni)
        af[ni] = *(const short8*)(wb + (wv * 2 + ni) * 512 + sw8);
#pragma unroll
      for (int mi = 0; mi < 2; ++mi) bx[mi] = *(const short8*)(hp[mi] + s * 32);
#pragma unroll
      for (int ni = 0; ni < 2; ++ni)
#pragma unroll
        for (int mi = 0; mi < 2; ++mi)
          acc[ni][mi] = __builtin_amdgcn_mfma_f32_16x16x32_bf16(af[ni], bx[mi], acc[ni][mi], 0, 0, 0);
    }
    const int n0 = wv * 32;
    float sv[2][4];
#pragma unroll
    for (int ni = 0; ni < 2; ++ni)
#pragma unroll
      for (int r = 0; r < 4; ++r) sv[ni][r] = 0.f;
#pragma unroll
    for (int mi = 0; mi < 2; ++mi) {
      const int r0 = row0 + mi * 16 + m16;
      if (r0 < M) {
        const float mk = mask[r0];
#pragma unroll
        for (int ni = 0; ni < 2; ++ni) {
          floatx4 bb = *(const floatx4*)&b3[n0 + ni * 16 + quad * 4];
#pragma unroll
          for (int r = 0; r < 4; ++r)
            sv[ni][r] += mk * lrelu(acc[ni][mi][r] + bb[r]);
        }
      }
    }
    // reduce over the 16 row-lanes (m16); xor keeps quad fixed
#pragma unroll
    for (int j = 1; j < 16; j <<= 1)
#pragma unroll
      for (int ni = 0; ni < 2; ++ni)
#pragma unroll
        for (int r = 0; r < 4; ++r)
          sv[ni][r] += __shfl_xor(sv[ni][r], j);
    if (m16 == 0) {
#pragma unroll
      for (int ni = 0; ni < 2; ++ni)
#pragma unroll
        for (int r = 0; r < 4; ++r)
          atomicAdd(out + s2Off + n0 + ni * 16 + quad * 4 + r, sv[ni][r]);
    }
  }
}

extern "C" void kernel_launch(void* const* d_in, const int* in_sizes, int n_in,
                              void* d_out, int out_size, void* d_ws, size_t ws_size,
                              hipStream_t stream) {
  (void)in_sizes; (void)n_in; (void)ws_size;
  constexpr int N_   = 100000;
  constexpr int MPAD = 100096;               // 1564 * 64
  constexpr int IND  = 128;
  constexpr int H1D  = 512;
  constexpr int H2D  = 512;
  constexpr int OUTD = 256;
  constexpr int NDAG = 2000;

  const float* X    = (const float*)d_in[0];
  const int*   dag  = (const int*)d_in[1];
  const float* mask = (const float*)d_in[2];
  const float* W1 = (const float*)d_in[3];
  const float* b1 = (const float*)d_in[4];
  const float* W2 = (const float*)d_in[5];
  const float* b2 = (const float*)d_in[6];
  const float* W3 = (const float*)d_in[7];
  const float* b3 = (const float*)d_in[8];
  const float* W4 = (const float*)d_in[9];
  const float* b4 = (const float*)d_in[10];
  const float* W5 = (const float*)d_in[11];
  const float* b5 = (const float*)d_in[12];
  const float* W6 = (const float*)d_in[13];
  const float* b6 = (const float*)d_in[14];

  char* ws = (char*)d_ws;
  auto alloc = [&](size_t bytes) {
    char* p = ws;
    ws += (bytes + 255) & ~(size_t)255;
    return p;
  };
  u16* W1t = (u16*)alloc((size_t)H1D * IND * 2);
  u16* W2t = (u16*)alloc((size_t)H2D * H1D * 2);
  u16* W3t = (u16*)alloc((size_t)OUTD * H2D * 2);
  u16* W4t = (u16*)alloc((size_t)H1D * OUTD * 2);
  u16* W5t = (u16*)alloc((size_t)H2D * H1D * 2);
  u16* W6t = (u16*)alloc((size_t)OUTD * H2D * 2);
  int* hist   = (int*)alloc((size_t)NDAG * 4);
  int* cursor = (int*)alloc((size_t)NDAG * 4);
  int* perm   = (int*)alloc((size_t)N_ * 4);
  int* dsort  = (int*)alloc((size_t)MPAD * 4);
  u16* Xb = (u16*)alloc((size_t)MPAD * IND * 2);

  float* out = (float*)d_out;
  float* s1  = out;                // [2000][256] f32, output 0
  const int s2Off = NDAG * OUTD;

  hipFuncSetAttribute(reinterpret_cast<const void*>(&node_fused),
                      hipFuncAttributeMaxDynamicSharedMemorySize, NODE_LDS);
  hipFuncSetAttribute(reinterpret_cast<const void*>(&fused3<OUTD>),
                      hipFuncAttributeMaxDynamicSharedMemorySize, FUSED_LDS);

  hipMemsetAsync(out, 0, (size_t)out_size * 4, stream);
  hipMemsetAsync(hist, 0, (size_t)NDAG * 4, stream);
  hipMemsetAsync(dsort + N_, 0xFF, (size_t)(MPAD - N_) * 4, stream);   // -1 tail
  hipMemsetAsync(Xb + (size_t)N_ * IND, 0, (size_t)(MPAD - N_) * IND * 2, stream);

  // counting sort by dag id
  hist_kernel<<<(N_ + 255) / 256, 256, 0, stream>>>(dag, hist, N_);
  scan_offsets<<<1, 256, 0, stream>>>(hist, cursor);
  scatter_kernel<<<(N_ + 255) / 256, 256, 0, stream>>>(dag, cursor, perm, dsort, N_);

  // weight transposes + X gather/convert
  transpose_all<<<dim3(16, 16, 6), 256, 0, stream>>>(W1, W2, W3, W4, W5, W6,
                                                     W1t, W2t, W3t, W4t, W5t, W6t);
  xb_conv<<<(N_ * 32 + 255) / 256, 256, 0, stream>>>(X, perm, Xb, N_);

  // fully fused node stack (L1+L2+L3+segment-sum), 64-row tiles, 2 blocks/CU
  node_fused<<<MPAD / NODE_ROWS, 512, NODE_LDS, stream>>>(Xb, W1t, W2t, W3t,
                                                          b1, b2, b3, s1, dsort);

  // global stack on s1 (f32 in d_out); s2 fused via atomics into out[s2Off..]
  fused3<OUTD><<<(NDAG + ROWS - 1) / ROWS, 512, FUSED_LDS, stream>>>(
      s1, W4t, W5t, W6t, b4, b5, b6, mask, out, s2Off, NDAG);
}

// Round 4
// 345.715 us; speedup vs baseline: 1.1860x; 1.1860x over previous
//
#include <hip/hip_runtime.h>
#include <hip/hip_bf16.h>

typedef unsigned short u16;
typedef __attribute__((ext_vector_type(8))) short short8;
typedef __attribute__((ext_vector_type(4))) short s4;
typedef __attribute__((ext_vector_type(4))) float floatx4;

__device__ __forceinline__ float lrelu(float x) { return x > 0.f ? x : 0.01f * x; }

__device__ __forceinline__ short bf16bits(float v) {
  __hip_bfloat16 t = __float2bfloat16(v);
  return *reinterpret_cast<short*>(&t);
}
__device__ __forceinline__ float bits2f(u16 b) {
  __hip_bfloat16 t = *reinterpret_cast<__hip_bfloat16*>(&b);
  return __bfloat162float(t);
}
__device__ __forceinline__ short8 pack8(floatx4 x0, floatx4 x1) {
  short8 b;
#pragma unroll
  for (int r = 0; r < 4; ++r) { b[r] = bf16bits(x0[r]); b[4 + r] = bf16bits(x1[r]); }
  return b;
}

__device__ __forceinline__ void gload_lds16(const void* g, void* lds) {
  __builtin_amdgcn_global_load_lds(
      (const __attribute__((address_space(1))) unsigned int*)g,
      (__attribute__((address_space(3))) unsigned int*)lds, 16, 0, 0);
}

// ---------------------------------------------------------------------------
// Fragment-pack W1/W2/W3: W[K][N] f32 -> P[(g*NS+s)*64 + lane][8] bf16 where
// g = col-group (16 cols), s = k-step (32 k), lane = quad*16+m16, element j:
//   P[(g*NS+s)*512 + lane*8 + j] = W[s*32 + quad*8 + j][g*16 + m16]
// A wave's af fragment load is then 64 lanes x 16B CONTIGUOUS (8 lines) vs
// 16 scattered lines with the row-major transpose.
// r3 BUG FIX: matrix selected by blockIdx.z; write index == local t (the same
// coordinates the content is derived from). r3 used the flat global index for
// the store -> W2p shifted +65536 u16, W3 pack stomped W5t (s2 absmax 599).
// ---------------------------------------------------------------------------
__global__ __launch_bounds__(256) void pack3(
    const float* __restrict__ W1, const float* __restrict__ W2,
    const float* __restrict__ W3,
    u16* __restrict__ P1, u16* __restrict__ P2, u16* __restrict__ P3) {
  const float* W; u16* P; int N, ls, total;
  switch (blockIdx.z) {
    case 0: W = W1; P = P1; N = 512; ls = 2; total = 8192;  break;  // K=128,NS=4
    case 1: W = W2; P = P2; N = 512; ls = 4; total = 32768; break;  // K=512,NS=16
    default: W = W3; P = P3; N = 256; ls = 4; total = 16384; break; // K=512,NS=16
  }
  const int t = blockIdx.x * 256 + threadIdx.x;
  if (t >= total) return;
  const int lane = t & 63;
  const int sg   = t >> 6;
  const int m16  = lane & 15;
  const int quad = lane >> 4;
  const int s    = sg & ((1 << ls) - 1);
  const int g    = sg >> ls;
  const int n    = g * 16 + m16;
  const int k0   = s * 32 + quad * 8;
  short8 out;
#pragma unroll
  for (int j = 0; j < 8; ++j) out[j] = bf16bits(W[(size_t)(k0 + j) * N + n]);
  *(short8*)(P + (size_t)t * 8) = out;
}

// ---------------------------------------------------------------------------
// Transpose+convert W4/W5/W6 -> row-major Wt[N][K] bf16 (fused3 layout).
// ---------------------------------------------------------------------------
__global__ __launch_bounds__(256) void transpose3(
    const float* __restrict__ W4, const float* __restrict__ W5,
    const float* __restrict__ W6,
    u16* __restrict__ T4, u16* __restrict__ T5, u16* __restrict__ T6) {
  const float* W; u16* T; int K, N;
  switch (blockIdx.z) {
    case 0: W = W4; T = T4; K = 256; N = 512; break;
    case 1: W = W5; T = T5; K = 512; N = 512; break;
    default: W = W6; T = T6; K = 512; N = 256; break;
  }
  if ((int)blockIdx.x >= N / 32 || (int)blockIdx.y >= K / 32) return;
  __shared__ u16 tile[32][33];
  const int tx = threadIdx.x & 31;
  const int ty = threadIdx.x >> 5;
  const int n0 = blockIdx.x * 32;
  const int k0 = blockIdx.y * 32;
  for (int i = ty; i < 32; i += 8)
    tile[i][tx] = (u16)bf16bits(W[(size_t)(k0 + i) * N + n0 + tx]);
  __syncthreads();
  for (int i = ty; i < 32; i += 8)
    T[(size_t)(n0 + i) * K + k0 + tx] = tile[tx][i];
}

// ---------------------------------------------------------------------------
// Counting sort of node ids by dag id (2000 bins).
// ---------------------------------------------------------------------------
__global__ __launch_bounds__(256) void hist_kernel(const int* __restrict__ dag,
                                                   int* __restrict__ hist, int n) {
  int i = blockIdx.x * blockDim.x + threadIdx.x;
  if (i < n) atomicAdd(&hist[dag[i]], 1);
}

__global__ __launch_bounds__(256) void scan_offsets(const int* __restrict__ hist,
                                                    int* __restrict__ cursor) {
  __shared__ int part[256];
  const int t = threadIdx.x;
  const int base = t * 8;
  int loc[8];
  int s = 0;
#pragma unroll
  for (int j = 0; j < 8; ++j) {
    int v = (base + j < 2000) ? hist[base + j] : 0;
    loc[j] = s;
    s += v;
  }
  part[t] = s;
  __syncthreads();
  int val = s;
  for (int off = 1; off < 256; off <<= 1) {
    int tmp = (t >= off) ? part[t - off] : 0;
    __syncthreads();
    val += tmp;
    part[t] = val;
    __syncthreads();
  }
  const int chunkBase = (t == 0) ? 0 : part[t - 1];
#pragma unroll
  for (int j = 0; j < 8; ++j)
    if (base + j < 2000) cursor[base + j] = chunkBase + loc[j];
}

__global__ __launch_bounds__(256) void scatter_kernel(const int* __restrict__ dag,
                                                      int* __restrict__ cursor,
                                                      int* __restrict__ perm,
                                                      int* __restrict__ dsort, int n) {
  int i = blockIdx.x * blockDim.x + threadIdx.x;
  if (i < n) {
    int d = dag[i];
    int p = atomicAdd(&cursor[d], 1);
    perm[p] = i;
    dsort[p] = d;
  }
}

// ---------------------------------------------------------------------------
// Gather X rows into sorted order AND fragment-pack (same chunk layout as
// pack3, 16-row granules): Xp[(tg*4+s)*512 + lane*8 + j] = bf16(X[perm[tg*16
// +m16]][s*32+quad*8+j]). Writes are 64x16B contiguous; reads are the
// inherent gather. Pad rows (>= n) write zeros (no separate memset needed).
// ---------------------------------------------------------------------------
__global__ __launch_bounds__(256) void xp_conv(const float* __restrict__ X,
                                               const int* __restrict__ perm,
                                               u16* __restrict__ Xp, int n) {
  const int t = blockIdx.x * 256 + threadIdx.x;    // (tg*4 + s)*64 + lane
  const int lane = t & 63;
  const int s    = (t >> 6) & 3;
  const int tg   = t >> 8;
  const int m16  = lane & 15;
  const int quad = lane >> 4;
  const int R    = tg * 16 + m16;
  short8 out = {0, 0, 0, 0, 0, 0, 0, 0};
  if (R < n) {
    const int src = perm[R];
    const float* xp = X + (size_t)src * 128 + s * 32 + quad * 8;
    out = pack8(*(const floatx4*)xp, *(const floatx4*)(xp + 4));
  }
  *(short8*)(Xp + (size_t)t * 8) = out;
}

// ---------------------------------------------------------------------------
// Persistent fused node stack. Grid=768 (3 blocks/CU via 49.9KB LDS), 512 thr
// (8 waves); blocks pull 48-row tiles off a global atomic counter (2086 tiles
// -> ~91% load balance, no relaunch, weights stay L1/L2-warm).
//   L1: H1 = lrelu(Xp@W1+b1)  K=128   af+bx packed-global (coalesced 16B/lane)
//   L2: H2 = lrelu(H1@W2+b2)  K=512   bx from LDS, af packed-global, prefetched
//   L3: G  = lrelu(H2@W3+b3)  K=512   -> LDS, segmented dag-sum -> atomics s1
// Per wave: 64 cols x 48 rows, acc[4|2][3]; ~120 VGPR @ launch_bounds(512,3)
// (r2 lesson: don't squeeze to 64 VGPR). af prefetch hides L2 latency.
// H pitch 520 u16 (row stride dwords = 260 === 4 mod 32 -> b128 reads 2-way).
// mfma(af, bx, acc): out row = bx-row (mi*16+m16), col = af-row (ni*16+quad*4+r).
// ---------------------------------------------------------------------------
#define NODE_ROWS 48
#define NODE_NP 520
#define NODE_P3 264
#define NODE_LDS (NODE_ROWS * NODE_NP * 2 + 16)   // 49936 B -> 3 blocks/CU

__global__ __launch_bounds__(512, 3) void node_fused(
    const u16* __restrict__ Xp, const u16* __restrict__ W1p,
    const u16* __restrict__ W2p, const u16* __restrict__ W3p,
    const float* __restrict__ b1, const float* __restrict__ b2,
    const float* __restrict__ b3, float* __restrict__ s1,
    const int* __restrict__ dsort, int* __restrict__ tilectr, int nTiles) {
  extern __shared__ __align__(16) char lds[];
  u16* H = (u16*)lds;   // [48][520] for H1/H2, reused as [48][264] for L3
  int* tileSlot = (int*)(lds + NODE_ROWS * NODE_NP * 2);

  const int tid  = threadIdx.x;
  const int wv   = tid >> 6;
  const int lane = tid & 63;
  const int m16  = lane & 15;
  const int quad = lane >> 4;

  // loop-invariant fragment base pointers (chunk = 512 u16 per (g,s))
  const u16* wp1 = W1p + (size_t)(wv * 4) * 2048 + lane * 8;   // g-stride 4*512
  const u16* wp2 = W2p + (size_t)(wv * 4) * 8192 + lane * 8;   // g-stride 16*512
  const u16* wp3 = W3p + (size_t)(wv * 2) * 8192 + lane * 8;

  for (;;) {
    if (tid == 0) *tileSlot = atomicAdd(tilectr, 1);
    __syncthreads();                      // also: all waves done with prev walk
    const int tile = *tileSlot;
    if (tile >= nTiles) return;           // uniform exit

    // ---- layer 1: K=128, N=512; bx from packed global Xp
    {
      const u16* xpp = Xp + (size_t)tile * 12 * 512 + lane * 8;
      floatx4 acc[4][3];
#pragma unroll
      for (int i = 0; i < 4; ++i)
#pragma unroll
        for (int j = 0; j < 3; ++j) { floatx4 z = {0.f, 0.f, 0.f, 0.f}; acc[i][j] = z; }
#pragma unroll
      for (int s = 0; s < 4; ++s) {
        short8 af[4], bx[3];
#pragma unroll
        for (int ni = 0; ni < 4; ++ni) af[ni] = *(const short8*)(wp1 + ni * 2048 + s * 512);
#pragma unroll
        for (int mi = 0; mi < 3; ++mi) bx[mi] = *(const short8*)(xpp + (mi * 4 + s) * 512);
#pragma unroll
        for (int ni = 0; ni < 4; ++ni)
#pragma unroll
          for (int mi = 0; mi < 3; ++mi)
            acc[ni][mi] = __builtin_amdgcn_mfma_f32_16x16x32_bf16(af[ni], bx[mi], acc[ni][mi], 0, 0, 0);
      }
      const int n0 = wv * 64;
#pragma unroll
      for (int ni = 0; ni < 4; ++ni) {
        const int nb = n0 + ni * 16 + quad * 4;
        floatx4 bb = *(const floatx4*)&b1[nb];
#pragma unroll
        for (int mi = 0; mi < 3; ++mi) {
          s4 h;
#pragma unroll
          for (int r = 0; r < 4; ++r) h[r] = bf16bits(lrelu(acc[ni][mi][r] + bb[r]));
          *(s4*)&H[(size_t)(mi * 16 + m16) * NODE_NP + nb] = h;
        }
      }
    }
    __syncthreads();

    // ---- layer 2: K=512, N=512; bx from LDS, af packed-global prefetched
    {
      const u16* hp = H + (size_t)m16 * NODE_NP + quad * 8;
      floatx4 acc[4][3];
#pragma unroll
      for (int i = 0; i < 4; ++i)
#pragma unroll
        for (int j = 0; j < 3; ++j) { floatx4 z = {0.f, 0.f, 0.f, 0.f}; acc[i][j] = z; }
      short8 af[4];
#pragma unroll
      for (int ni = 0; ni < 4; ++ni) af[ni] = *(const short8*)(wp2 + ni * 8192);
#pragma unroll 2
      for (int s = 0; s < 16; ++s) {
        short8 bx[3];
#pragma unroll
        for (int mi = 0; mi < 3; ++mi)
          bx[mi] = *(const short8*)(hp + mi * (16 * NODE_NP) + s * 32);
        short8 afn[4];
        const int sn = (s + 1) & 15;   // s=15 wraps: dead reload, branchless
#pragma unroll
        for (int ni = 0; ni < 4; ++ni) afn[ni] = *(const short8*)(wp2 + ni * 8192 + sn * 512);
#pragma unroll
        for (int ni = 0; ni < 4; ++ni)
#pragma unroll
          for (int mi = 0; mi < 3; ++mi)
            acc[ni][mi] = __builtin_amdgcn_mfma_f32_16x16x32_bf16(af[ni], bx[mi], acc[ni][mi], 0, 0, 0);
#pragma unroll
        for (int ni = 0; ni < 4; ++ni) af[ni] = afn[ni];
      }
      __syncthreads();   // all waves done reading H1 before overwriting
      const int n0 = wv * 64;
#pragma unroll
      for (int ni = 0; ni < 4; ++ni) {
        const int nb = n0 + ni * 16 + quad * 4;
        floatx4 bb = *(const floatx4*)&b2[nb];
#pragma unroll
        for (int mi = 0; mi < 3; ++mi) {
          s4 h;
#pragma unroll
          for (int r = 0; r < 4; ++r) h[r] = bf16bits(lrelu(acc[ni][mi][r] + bb[r]));
          *(s4*)&H[(size_t)(mi * 16 + m16) * NODE_NP + nb] = h;
        }
      }
    }
    __syncthreads();

    // ---- layer 3: K=512, N=256; wave cols [wv*32, wv*32+32)
    {
      const u16* hp = H + (size_t)m16 * NODE_NP + quad * 8;
      floatx4 acc[2][3];
#pragma unroll
      for (int i = 0; i < 2; ++i)
#pragma unroll
        for (int j = 0; j < 3; ++j) { floatx4 z = {0.f, 0.f, 0.f, 0.f}; acc[i][j] = z; }
      short8 af[2];
#pragma unroll
      for (int ni = 0; ni < 2; ++ni) af[ni] = *(const short8*)(wp3 + ni * 8192);
#pragma unroll 2
      for (int s = 0; s < 16; ++s) {
        short8 bx[3];
#pragma unroll
        for (int mi = 0; mi < 3; ++mi)
          bx[mi] = *(const short8*)(hp + mi * (16 * NODE_NP) + s * 32);
        short8 afn[2];
        const int sn = (s + 1) & 15;
#pragma unroll
        for (int ni = 0; ni < 2; ++ni) afn[ni] = *(const short8*)(wp3 + ni * 8192 + sn * 512);
#pragma unroll
        for (int ni = 0; ni < 2; ++ni)
#pragma unroll
          for (int mi = 0; mi < 3; ++mi)
            acc[ni][mi] = __builtin_amdgcn_mfma_f32_16x16x32_bf16(af[ni], bx[mi], acc[ni][mi], 0, 0, 0);
#pragma unroll
        for (int ni = 0; ni < 2; ++ni) af[ni] = afn[ni];
      }
      __syncthreads();   // all waves done reading H2
      const int n0 = wv * 32;
#pragma unroll
      for (int ni = 0; ni < 2; ++ni) {
        const int nb = n0 + ni * 16 + quad * 4;
        floatx4 bb = *(const floatx4*)&b3[nb];
#pragma unroll
        for (int mi = 0; mi < 3; ++mi) {
          s4 h;
#pragma unroll
          for (int r = 0; r < 4; ++r) h[r] = bf16bits(lrelu(acc[ni][mi][r] + bb[r]));
          *(s4*)&H[(size_t)(mi * 16 + m16) * NODE_P3 + nb] = h;
        }
      }
    }
    __syncthreads();

    // ---- segmented dag walk: wave wv owns rows [(wv>>2)*24, +24), cols
    // [(wv&3)*64, +64); lane = local col. dsort sorted; -1 (pad) skipped.
    // (lanes 24..31 load dag ids they never shfl; dsort has +64 tail pad)
    {
      const int rh = (wv >> 2) * 24;
      const int c0 = (wv & 3) * 64;
      const int myDag = dsort[(size_t)tile * NODE_ROWS + rh + (lane & 31)];
      float* so = s1 + c0 + lane;
      float run = 0.f;
      int cur = __shfl(myDag, 0);
#pragma unroll
      for (int rb = 0; rb < 24; rb += 8) {
        float v[8];
#pragma unroll
        for (int j = 0; j < 8; ++j)
          v[j] = bits2f(H[(size_t)(rh + rb + j) * NODE_P3 + c0 + lane]);
#pragma unroll
        for (int j = 0; j < 8; ++j) {
          int d = __shfl(myDag, rb + j);              // wave-uniform
          if (d != cur) {
            if (cur >= 0) atomicAdd(so + (size_t)cur * 256, run);
            run = 0.f; cur = d;
          }
          run += v[j];
        }
      }
      if (cur >= 0) atomicAdd(so + (size_t)cur * 256, run);
    }
  }
}

// ---------------------------------------------------------------------------
// Fused 3-layer global stack (2000 rows) + fused s2 = mask @ g3 reduction.
// ---------------------------------------------------------------------------
#define ROWS 32
#define H_PITCH 520
#define HBYTES (ROWS * H_PITCH * 2)
#define WL_OFF (2 * HBYTES)
#define WL_HALF 16384
#define FUSED_LDS (WL_OFF + 65536 + 128)

template <int K1>
__global__ __launch_bounds__(512, 2) void fused3(
    const float* __restrict__ A0, const u16* __restrict__ W1t,
    const u16* __restrict__ W2t, const u16* __restrict__ W3t,
    const float* __restrict__ b1, const float* __restrict__ b2,
    const float* __restrict__ b3, const float* __restrict__ mask,
    float* __restrict__ out, int s2Off, int M) {
  extern __shared__ __align__(16) char ldsbuf[];
  u16* H1 = (u16*)ldsbuf;
  u16* H2 = (u16*)(ldsbuf + HBYTES);
  u16* Wl = (u16*)(ldsbuf + WL_OFF);

  const int tid  = threadIdx.x;
  const int wv   = tid >> 6;
  const int lane = tid & 63;
  const int m16  = lane & 15;
  const int quad = lane >> 4;
  const int row0 = blockIdx.x * ROWS;

  const int sr  = lane >> 2;
  const int skq = ((lane & 3) - (sr >> 1)) & 3;
  const int sw8 = (m16 * 4 + ((quad + (m16 >> 1)) & 3)) * 8;

  auto stage512 = [&](const u16* Wt, int K, int k0, int sel) {
    u16* base = Wl + sel * WL_HALF;
#pragma unroll
    for (int c = 0; c < 4; ++c) {
      int chunk = wv * 4 + c;
      gload_lds16(Wt + (size_t)(chunk * 16 + sr) * K + k0 + skq * 8,
                  base + chunk * 512);
    }
  };
  auto stage256 = [&](const u16* Wt, int K, int k0, int sel) {
    u16* base = Wl + sel * 8192;
#pragma unroll
    for (int c = 0; c < 2; ++c) {
      int chunk = wv * 2 + c;
      gload_lds16(Wt + (size_t)(chunk * 16 + sr) * K + k0 + skq * 8,
                  base + chunk * 512);
    }
  };

  int grow[2];
#pragma unroll
  for (int mi = 0; mi < 2; ++mi) {
    int r = row0 + mi * 16 + m16;
    grow[mi] = r < M ? r : (M - 1);
  }
  const float* ap[2];
#pragma unroll
  for (int mi = 0; mi < 2; ++mi) ap[mi] = A0 + (size_t)grow[mi] * K1 + quad * 8;

  {  // layer 1
    constexpr int NS1 = K1 / 32;
    stage512(W1t, K1, 0, 0);
    floatx4 acc[4][2];
#pragma unroll
    for (int i = 0; i < 4; i++)
#pragma unroll
      for (int j = 0; j < 2; j++) { floatx4 z = {0.f,0.f,0.f,0.f}; acc[i][j] = z; }
#pragma unroll
    for (int s = 0; s < NS1; ++s) {
      __syncthreads();
      if (s + 1 < NS1) stage512(W1t, K1, (s + 1) * 32, (s + 1) & 1);
      const u16* wb = Wl + (s & 1) * WL_HALF;
      short8 af[4], bx[2];
#pragma unroll
      for (int ni = 0; ni < 4; ++ni)
        af[ni] = *(const short8*)(wb + (wv * 4 + ni) * 512 + sw8);
#pragma unroll
      for (int mi = 0; mi < 2; ++mi)
        bx[mi] = pack8(*(const floatx4*)(ap[mi] + s * 32),
                       *(const floatx4*)(ap[mi] + s * 32 + 4));
#pragma unroll
      for (int ni = 0; ni < 4; ++ni)
#pragma unroll
        for (int mi = 0; mi < 2; ++mi)
          acc[ni][mi] = __builtin_amdgcn_mfma_f32_16x16x32_bf16(af[ni], bx[mi], acc[ni][mi], 0, 0, 0);
    }
    const int n0 = wv * 64;
#pragma unroll
    for (int ni = 0; ni < 4; ++ni) {
      const int nb = n0 + ni * 16 + quad * 4;
      floatx4 bb = *(const floatx4*)&b1[nb];
#pragma unroll
      for (int mi = 0; mi < 2; ++mi) {
        s4 h;
#pragma unroll
        for (int r = 0; r < 4; ++r) h[r] = bf16bits(lrelu(acc[ni][mi][r] + bb[r]));
        *(s4*)&H1[(mi * 16 + m16) * H_PITCH + nb] = h;
      }
    }
  }

  {  // layer 2
    stage512(W2t, 512, 0, 0);
    const u16* hp[2];
#pragma unroll
    for (int mi = 0; mi < 2; ++mi)
      hp[mi] = H1 + (mi * 16 + m16) * H_PITCH + quad * 8;
    floatx4 acc[4][2];
#pragma unroll
    for (int i = 0; i < 4; i++)
#pragma unroll
      for (int j = 0; j < 2; j++) { floatx4 z = {0.f,0.f,0.f,0.f}; acc[i][j] = z; }
    for (int s = 0; s < 16; ++s) {
      __syncthreads();
      if (s < 15) stage512(W2t, 512, (s + 1) * 32, (s + 1) & 1);
      const u16* wb = Wl + (s & 1) * WL_HALF;
      short8 af[4], bx[2];
#pragma unroll
      for (int ni = 0; ni < 4; ++ni)
        af[ni] = *(const short8*)(wb + (wv * 4 + ni) * 512 + sw8);
#pragma unroll
      for (int mi = 0; mi < 2; ++mi) bx[mi] = *(const short8*)(hp[mi] + s * 32);
#pragma unroll
      for (int ni = 0; ni < 4; ++ni)
#pragma unroll
        for (int mi = 0; mi < 2; ++mi)
          acc[ni][mi] = __builtin_amdgcn_mfma_f32_16x16x32_bf16(af[ni], bx[mi], acc[ni][mi], 0, 0, 0);
    }
    const int n0 = wv * 64;
#pragma unroll
    for (int ni = 0; ni < 4; ++ni) {
      const int nb = n0 + ni * 16 + quad * 4;
      floatx4 bb = *(const floatx4*)&b2[nb];
#pragma unroll
      for (int mi = 0; mi < 2; ++mi) {
        s4 h;
#pragma unroll
        for (int r = 0; r < 4; ++r) h[r] = bf16bits(lrelu(acc[ni][mi][r] + bb[r]));
        *(s4*)&H2[(mi * 16 + m16) * H_PITCH + nb] = h;
      }
    }
  }

  {  // layer 3 + fused s2 contribution
    stage256(W3t, 512, 0, 0);
    const u16* hp[2];
#pragma unroll
    for (int mi = 0; mi < 2; ++mi)
      hp[mi] = H2 + (mi * 16 + m16) * H_PITCH + quad * 8;
    floatx4 acc[2][2];
#pragma unroll
    for (int i = 0; i < 2; i++)
#pragma unroll
      for (int j = 0; j < 2; j++) { floatx4 z = {0.f,0.f,0.f,0.f}; acc[i][j] = z; }
    for (int s = 0; s < 16; ++s) {
      __syncthreads();
      if (s < 15) stage256(W3t, 512, (s + 1) * 32, (s + 1) & 1);
      const u16* wb = Wl + (s & 1) * 8192;
      short8 af[2], bx[2];
#pragma unroll
      for (int ni = 0; ni < 2; ++ni)
        af[ni] = *(const short8*)(wb + (wv * 2 + ni) * 512 + sw8);
#pragma unroll
      for (int mi = 0; mi < 2; ++mi) bx[mi] = *(const short8*)(hp[mi] + s * 32);
#pragma unroll
      for (int ni = 0; ni < 2; ++ni)
#pragma unroll
        for (int mi = 0; mi < 2; ++mi)
          acc[ni][mi] = __builtin_amdgcn_mfma_f32_16x16x32_bf16(af[ni], bx[mi], acc[ni][mi], 0, 0, 0);
    }
    const int n0 = wv * 32;
    float sv[2][4];
#pragma unroll
    for (int ni = 0; ni < 2; ++ni)
#pragma unroll
      for (int r = 0; r < 4; ++r) sv[ni][r] = 0.f;
#pragma unroll
    for (int mi = 0; mi < 2; ++mi) {
      const int r0 = row0 + mi * 16 + m16;
      if (r0 < M) {
        const float mk = mask[r0];
#pragma unroll
        for (int ni = 0; ni < 2; ++ni) {
          floatx4 bb = *(const floatx4*)&b3[n0 + ni * 16 + quad * 4];
#pragma unroll
          for (int r = 0; r < 4; ++r)
            sv[ni][r] += mk * lrelu(acc[ni][mi][r] + bb[r]);
        }
      }
    }
#pragma unroll
    for (int j = 1; j < 16; j <<= 1)
#pragma unroll
      for (int ni = 0; ni < 2; ++ni)
#pragma unroll
        for (int r = 0; r < 4; ++r)
          sv[ni][r] += __shfl_xor(sv[ni][r], j);
    if (m16 == 0) {
#pragma unroll
      for (int ni = 0; ni < 2; ++ni)
#pragma unroll
        for (int r = 0; r < 4; ++r)
          atomicAdd(out + s2Off + n0 + ni * 16 + quad * 4 + r, sv[ni][r]);
    }
  }
}

extern "C" void kernel_launch(void* const* d_in, const int* in_sizes, int n_in,
                              void* d_out, int out_size, void* d_ws, size_t ws_size,
                              hipStream_t stream) {
  (void)in_sizes; (void)n_in; (void)ws_size;
  constexpr int N_    = 100000;
  constexpr int MPAD  = 100128;              // 2086 * 48, also 6258 * 16
  constexpr int NTILE = MPAD / 48;           // 2086
  constexpr int NGRAN = MPAD / 16;           // 6258
  constexpr int IND   = 128;
  constexpr int H1D   = 512;
  constexpr int H2D   = 512;
  constexpr int OUTD  = 256;
  constexpr int NDAG  = 2000;

  const float* X    = (const float*)d_in[0];
  const int*   dag  = (const int*)d_in[1];
  const float* mask = (const float*)d_in[2];
  const float* W1 = (const float*)d_in[3];
  const float* b1 = (const float*)d_in[4];
  const float* W2 = (const float*)d_in[5];
  const float* b2 = (const float*)d_in[6];
  const float* W3 = (const float*)d_in[7];
  const float* b3 = (const float*)d_in[8];
  const float* W4 = (const float*)d_in[9];
  const float* b4 = (const float*)d_in[10];
  const float* W5 = (const float*)d_in[11];
  const float* b5 = (const float*)d_in[12];
  const float* W6 = (const float*)d_in[13];
  const float* b6 = (const float*)d_in[14];

  char* ws = (char*)d_ws;
  auto alloc = [&](size_t bytes) {
    char* p = ws;
    ws += (bytes + 255) & ~(size_t)255;
    return p;
  };
  u16* W1p = (u16*)alloc((size_t)H1D * IND * 2);    // packed fragment layout
  u16* W2p = (u16*)alloc((size_t)H2D * H1D * 2);
  u16* W3p = (u16*)alloc((size_t)OUTD * H2D * 2);
  u16* W4t = (u16*)alloc((size_t)H1D * OUTD * 2);   // row-major transpose (fused3)
  u16* W5t = (u16*)alloc((size_t)H2D * H1D * 2);
  u16* W6t = (u16*)alloc((size_t)OUTD * H2D * 2);
  int* hist    = (int*)alloc((size_t)NDAG * 4);
  int* cursor  = (int*)alloc((size_t)NDAG * 4);
  int* perm    = (int*)alloc((size_t)N_ * 4);
  int* dsort   = (int*)alloc((size_t)(MPAD + 64) * 4);
  int* tilectr = (int*)alloc(256);
  u16* Xp = (u16*)alloc((size_t)MPAD * IND * 2);    // packed fragment layout

  float* out = (float*)d_out;
  float* s1  = out;                // [2000][256] f32, output 0
  const int s2Off = NDAG * OUTD;

  hipFuncSetAttribute(reinterpret_cast<const void*>(&node_fused),
                      hipFuncAttributeMaxDynamicSharedMemorySize, NODE_LDS);
  hipFuncSetAttribute(reinterpret_cast<const void*>(&fused3<OUTD>),
                      hipFuncAttributeMaxDynamicSharedMemorySize, FUSED_LDS);

  hipMemsetAsync(out, 0, (size_t)out_size * 4, stream);
  hipMemsetAsync(hist, 0, (size_t)NDAG * 4, stream);
  hipMemsetAsync(tilectr, 0, 256, stream);
  hipMemsetAsync(dsort + N_, 0xFF, (size_t)(MPAD + 64 - N_) * 4, stream);  // -1 tail

  // counting sort by dag id
  hist_kernel<<<(N_ + 255) / 256, 256, 0, stream>>>(dag, hist, N_);
  scan_offsets<<<1, 256, 0, stream>>>(hist, cursor);
  scatter_kernel<<<(N_ + 255) / 256, 256, 0, stream>>>(dag, cursor, perm, dsort, N_);

  // weight prep: fragment-pack W1..W3 (z-indexed), row-major transpose W4..W6
  pack3<<<dim3(128, 1, 3), 256, 0, stream>>>(W1, W2, W3, W1p, W2p, W3p);
  transpose3<<<dim3(16, 16, 3), 256, 0, stream>>>(W4, W5, W6, W4t, W5t, W6t);

  // gather + fragment-pack X (pad rows write zeros)
  xp_conv<<<NGRAN, 256, 0, stream>>>(X, perm, Xp, N_);

  // persistent fused node stack: 768 blocks (3/CU), work-stealing over tiles
  node_fused<<<768, 512, NODE_LDS, stream>>>(Xp, W1p, W2p, W3p,
                                             b1, b2, b3, s1, dsort,
                                             tilectr, NTILE);

  // global stack on s1 (f32 in d_out); s2 fused via atomics into out[s2Off..]
  fused3<OUTD><<<(NDAG + ROWS - 1) / ROWS, 512, FUSED_LDS, stream>>>(
      s1, W4t, W5t, W6t, b4, b5, b6, mask, out, s2Off, NDAG);
}